// Round 1
// 619.329 us; speedup vs baseline: 1.0399x; 1.0399x over previous
//
#include <hip/hip_runtime.h>

// B=16384, T=56, F=56, H=20, 3H=60, FC1=128, NC=2
// R5: scan inner loop re-packed with v_pk_fma_f32 (VOP3P packed fp32):
//  - weights held as f32x2 pairs, h broadcasts consumed as SGPR pairs
//  - hmA readlane broadcasts persisted in SGPR pairs (hA2) and reused by BOTH
//    layer-1's ih-dot and the NEXT step's layer-0 hh-dot (60 -> 40 readlanes
//    per (t,elem); 60 -> 30 fma issues, moved to the packed pipe).

#define Bsz  16384
#define Tt   56
#define Ff   56
#define Hh   20
#define Gg   60
#define FC1n 128
#define THn  1120  // T*H
#define BT   (Bsz * Tt)

// ws float layout: [0..2239] weff, [2240..2241] beff, [2242..5601] WT (14*60*4),
// [5632 ..) xp (BT*60 floats)
#define WS_WEFF 0
#define WS_BEFF 2240
#define WS_WT   2242
#define WS_XP   5632
#define WS_NEED_BYTES ((size_t)(WS_XP + (size_t)BT * Gg) * 4)

typedef __attribute__((address_space(1))) const unsigned char gas_uchar;
typedef __attribute__((address_space(3))) unsigned char las_uchar;
typedef __attribute__((ext_vector_type(2))) float f32x2;

__device__ __forceinline__ float rdlane(float v, int l) {
  return __uint_as_float(__builtin_amdgcn_readlane(__float_as_uint(v), l));
}
__device__ __forceinline__ float bperm(int addr, float v) {
  return __uint_as_float(__builtin_amdgcn_ds_bpermute(addr, __float_as_uint(v)));
}
__device__ __forceinline__ float fast_rcp(float x) { return __builtin_amdgcn_rcpf(x); }
__device__ __forceinline__ float sigmoid_fast(float x) { return fast_rcp(1.0f + __expf(-x)); }
__device__ __forceinline__ float tanh_fast(float x) { return 1.0f - 2.0f * fast_rcp(1.0f + __expf(2.0f * x)); }

// packed fma: d = hs * wv + c ; hs is a wave-uniform SGPR pair (the h
// broadcasts), wv/c are VGPR pairs. One instr = 2 MACs per lane.
__device__ __forceinline__ f32x2 pkfma(f32x2 hs, f32x2 wv, f32x2 c) {
  f32x2 d;
  asm("v_pk_fma_f32 %0, %1, %2, %3" : "=v"(d) : "s"(hs), "v"(wv), "v"(c));
  return d;
}

__device__ __forceinline__ void gru_cell(float xg, float hg, int addrR, int addrZ, float& hm) {
  float sg = sigmoid_fast(xg + hg);     // r on lanes 0..19, z on 20..39
  float rr = bperm(addrR, sg);
  float nn = tanh_fast(fmaf(rr, hg, xg));
  float zz = bperm(addrZ, sg);
  hm = fmaf(zz, hm - nn, nn);           // n + z*(h-n)
}

// ---------------- prep: W_eff, b_eff, and transposed/chunked W_ih0 ----------------
__global__ void prep_all(const float* __restrict__ Wfc1, const float* __restrict__ bfc1,
                         const float* __restrict__ Wfc2, const float* __restrict__ bfc2,
                         const float* __restrict__ Wih0, float* __restrict__ ws) {
  int i = blockIdx.x * blockDim.x + threadIdx.x;
  if (i < THn) {
    float s0a = 0.f, s1a = 0.f, s0b = 0.f, s1b = 0.f;
    float s0c = 0.f, s1c = 0.f, s0d = 0.f, s1d = 0.f;
#pragma unroll 4
    for (int j = 0; j < FC1n; j += 4) {
      float wa = Wfc1[(j + 0) * THn + i];
      float wb = Wfc1[(j + 1) * THn + i];
      float wc = Wfc1[(j + 2) * THn + i];
      float wd = Wfc1[(j + 3) * THn + i];
      s0a = fmaf(wa, Wfc2[j + 0], s0a); s1a = fmaf(wa, Wfc2[FC1n + j + 0], s1a);
      s0b = fmaf(wb, Wfc2[j + 1], s0b); s1b = fmaf(wb, Wfc2[FC1n + j + 1], s1b);
      s0c = fmaf(wc, Wfc2[j + 2], s0c); s1c = fmaf(wc, Wfc2[FC1n + j + 2], s1c);
      s0d = fmaf(wd, Wfc2[j + 3], s0d); s1d = fmaf(wd, Wfc2[FC1n + j + 3], s1d);
    }
    ws[WS_WEFF + i * 2 + 0] = (s0a + s0b) + (s0c + s0d);
    ws[WS_WEFF + i * 2 + 1] = (s1a + s1b) + (s1c + s1d);
  } else if (i < THn + 2) {
    int c = i - THn;
    float s = bfc2[c];
    for (int j = 0; j < FC1n; ++j) s = fmaf(bfc1[j], Wfc2[c * FC1n + j], s);
    ws[WS_BEFF + c] = s;
  } else if (i < THn + 2 + 14 * Gg * 4) {
    int j = i - (THn + 2);          // j = f4*240 + g*4 + c
    int f4 = j / 240;
    int rem = j % 240;
    int g = rem / 4, c = rem % 4;
    ws[WS_WT + j] = Wih0[g * Ff + f4 * 4 + c];
  }
}

// ---------------- xproj v2: LDS-staged x ----------------
#define PadW 57
__global__ __launch_bounds__(256, 2) void xproj_kernel(
    const float* __restrict__ x, const float* __restrict__ bih0,
    const float* __restrict__ wschunk /* ws+WS_WT */, float* __restrict__ xp) {
  __shared__ float xs[256 * PadW];  // 58368 B
  const int tid = threadIdx.x;
  const size_t blk0 = (size_t)blockIdx.x * 256;  // first row of this block

  const float4* xg = (const float4*)(x + blk0 * Ff);
#pragma unroll
  for (int i = 0; i < 14; ++i) {
    int p = i * 256 + tid;
    float4 v = xg[p];                 // coalesced 16B/lane
    int r = p / 14, c = p % 14;
    *(float4*)&xs[r * PadW + c * 4] = v;
  }
  __syncthreads();

  float acc[Gg];
#pragma unroll
  for (int g = 0; g < Gg; ++g) acc[g] = bih0[g];  // uniform -> s_load

  const float4* wt = (const float4*)wschunk;  // [14][60] float4, wave-uniform
#pragma unroll 1
  for (int f4 = 0; f4 < 14; ++f4) {
    float4 xv = *(const float4*)&xs[tid * PadW + f4 * 4];
    const float4* wb = wt + f4 * Gg;
#pragma unroll
    for (int g = 0; g < Gg; ++g) {
      float4 w = wb[g];
      acc[g] = fmaf(xv.x, w.x, fmaf(xv.y, w.y, fmaf(xv.z, w.z, fmaf(xv.w, w.w, acc[g]))));
    }
  }
  float4* out = (float4*)(xp + (blk0 + tid) * Gg);
#pragma unroll
  for (int q = 0; q < 15; ++q)
    out[q] = make_float4(acc[4 * q], acc[4 * q + 1], acc[4 * q + 2], acc[4 * q + 3]);
}

// ---------------- scan: 4 elems/wave, packed-fp32 dots, persisted broadcasts ----------------
__global__ __launch_bounds__(256, 4) void gru_scan_xp4(
    const float* __restrict__ xp,
    const float* __restrict__ Whh0, const float* __restrict__ bhh0,
    const float* __restrict__ Wih1, const float* __restrict__ bih1,
    const float* __restrict__ Whh1, const float* __restrict__ bhh1,
    const float* __restrict__ ws, float* __restrict__ y) {
  __shared__ float weff[2 * THn + 2];
  for (int idx = threadIdx.x; idx < 2 * THn + 2; idx += 256) weff[idx] = ws[idx];
  __syncthreads();

  const int lane = threadIdx.x & 63;
  const int wv = threadIdx.x >> 6;
  const int b0 = (blockIdx.x * 4 + wv) * 4;  // elems b0..b0+3
  const int g = (lane < Gg) ? lane : 0;

  // per-lane weight rows as f32x2 pairs over k (aligned: (g*20+2i)*4 % 8 == 0)
  f32x2 whh0p[10], wih1p[10], whh1p[10];
#pragma unroll
  for (int i = 0; i < 10; ++i) whh0p[i] = *(const f32x2*)&Whh0[g * Hh + 2 * i];
#pragma unroll
  for (int i = 0; i < 10; ++i) wih1p[i] = *(const f32x2*)&Wih1[g * Hh + 2 * i];
#pragma unroll
  for (int i = 0; i < 10; ++i) whh1p[i] = *(const f32x2*)&Whh1[g * Hh + 2 * i];

  const f32x2 cb0  = {bhh0[g], 0.f};
  const f32x2 cb1i = {bih1[g], 0.f};
  const f32x2 cb1h = {bhh1[g], 0.f};
  const f32x2 zz2  = {0.f, 0.f};

  float hmA[4] = {0.f, 0.f, 0.f, 0.f};
  float hmB[4] = {0.f, 0.f, 0.f, 0.f};
  // persisted SGPR-pair broadcasts of hmA (layer-0 output); reused by layer-1's
  // ih-dot at step t AND layer-0's hh-dot at step t+1.
  f32x2 hA2[4][10];
#pragma unroll
  for (int e = 0; e < 4; ++e)
#pragma unroll
    for (int i = 0; i < 10; ++i) hA2[e][i] = zz2;

  float ya[4] = {0.f, 0.f, 0.f, 0.f};
  float yb[4] = {0.f, 0.f, 0.f, 0.f};

  const int addrR = ((lane >= 40) ? (lane - 40) : lane) * 4;
  const int addrZ = ((lane >= 40) ? (lane - 20) : lane) * 4;
  const int jm = (lane >= 40 && lane < Gg) ? lane - 40 : 0;

  // one SGPR base + per-lane VGPR offsets (keeps SGPR budget for hA2)
  const float* xpb = xp + (size_t)b0 * (Tt * Gg);
  int off[4];
  float xc[4], xn[4];
#pragma unroll
  for (int e = 0; e < 4; ++e) { off[e] = e * (Tt * Gg) + g; xc[e] = xpb[off[e]]; }

#pragma unroll 1
  for (int t = 0; t < Tt; ++t) {
    if (t < Tt - 1) {  // uniform branch: prefetch next step's xp
#pragma unroll
      for (int e = 0; e < 4; ++e) xn[e] = xpb[off[e] + Gg];
    }
    // ---- layer 0: hg = Whh0 . h1(t-1) + bh0, no readlanes (hA2 reused) ----
#pragma unroll
    for (int e = 0; e < 4; ++e) {
      f32x2 a = pkfma(hA2[e][0], whh0p[0], cb0);
      f32x2 b = pkfma(hA2[e][1], whh0p[1], zz2);
#pragma unroll
      for (int i = 2; i < 10; i += 2) {
        a = pkfma(hA2[e][i], whh0p[i], a);
        b = pkfma(hA2[e][i + 1], whh0p[i + 1], b);
      }
      float hg = (a.x + b.x) + (a.y + b.y);
      gru_cell(xc[e], hg, addrR, addrZ, hmA[e]);
      // refresh broadcasts of the NEW hmA into SGPR pairs
#pragma unroll
      for (int i = 0; i < 10; ++i) {
        f32x2 hp;
        hp.x = rdlane(hmA[e], 40 + 2 * i);
        hp.y = rdlane(hmA[e], 41 + 2 * i);
        hA2[e][i] = hp;
      }
    }
    // ---- layer 1: ig = Wih1 . h1(t) (hA2 reuse), hg = Whh1 . h2(t-1) ----
#pragma unroll
    for (int e = 0; e < 4; ++e) {
      f32x2 ai = pkfma(hA2[e][0], wih1p[0], cb1i);
      f32x2 bi = pkfma(hA2[e][1], wih1p[1], zz2);
      f32x2 h0; h0.x = rdlane(hmB[e], 40); h0.y = rdlane(hmB[e], 41);
      f32x2 ah = pkfma(h0, whh1p[0], cb1h);
      f32x2 h1; h1.x = rdlane(hmB[e], 42); h1.y = rdlane(hmB[e], 43);
      f32x2 bh = pkfma(h1, whh1p[1], zz2);
#pragma unroll
      for (int i = 2; i < 10; i += 2) {
        ai = pkfma(hA2[e][i], wih1p[i], ai);
        bi = pkfma(hA2[e][i + 1], wih1p[i + 1], bi);
        f32x2 he; he.x = rdlane(hmB[e], 40 + 2 * i); he.y = rdlane(hmB[e], 41 + 2 * i);
        ah = pkfma(he, whh1p[i], ah);
        f32x2 ho; ho.x = rdlane(hmB[e], 42 + 2 * i); ho.y = rdlane(hmB[e], 43 + 2 * i);
        bh = pkfma(ho, whh1p[i + 1], bh);
      }
      float ig = (ai.x + bi.x) + (ai.y + bi.y);
      float hg = (ah.x + bh.x) + (ah.y + bh.y);
      gru_cell(ig, hg, addrR, addrZ, hmB[e]);
    }
    // ---- FC accumulation (lane 40+j holds h2[t][j]) ----
    {
      float2 wv2 = *(const float2*)&weff[(t * Hh + jm) * 2];
#pragma unroll
      for (int e = 0; e < 4; ++e) {
        ya[e] = fmaf(hmB[e], wv2.x, ya[e]);
        yb[e] = fmaf(hmB[e], wv2.y, yb[e]);
      }
    }
#pragma unroll
    for (int e = 0; e < 4; ++e) { xc[e] = xn[e]; off[e] += Gg; }
  }

  const bool active = (lane >= 40 && lane < Gg);
#pragma unroll
  for (int e = 0; e < 4; ++e) {
    if (!active) { ya[e] = 0.f; yb[e] = 0.f; }
  }
#pragma unroll
  for (int off2 = 32; off2 >= 1; off2 >>= 1) {
#pragma unroll
    for (int e = 0; e < 4; ++e) {
      ya[e] += __shfl_xor(ya[e], off2, 64);
      yb[e] += __shfl_xor(yb[e], off2, 64);
    }
  }
  if (lane == 0) {
    float be0 = weff[WS_BEFF], be1 = weff[WS_BEFF + 1];
    float4 o0 = make_float4(ya[0] + be0, yb[0] + be1, ya[1] + be0, yb[1] + be1);
    float4 o1 = make_float4(ya[2] + be0, yb[2] + be1, ya[3] + be0, yb[3] + be1);
    float4* yo = (float4*)(y + (size_t)b0 * 2);
    yo[0] = o0;
    yo[1] = o1;
  }
}

// ---------------- fallback scan (ws too small for xp) ----------------
__global__ __launch_bounds__(256) void gru_scan_fb(
    const float* __restrict__ x,
    const float* __restrict__ Wih0, const float* __restrict__ Whh0,
    const float* __restrict__ bih0, const float* __restrict__ bhh0,
    const float* __restrict__ Wih1, const float* __restrict__ Whh1,
    const float* __restrict__ bih1, const float* __restrict__ bhh1,
    const float* __restrict__ ws, float* __restrict__ y) {
  __shared__ float weff[2 * THn];
  __shared__ __align__(16) float xstage[4][2][Ff];
  for (int idx = threadIdx.x; idx < 2 * THn; idx += 256) weff[idx] = ws[idx];
  __syncthreads();

  const int lane = threadIdx.x & 63;
  const int wv = threadIdx.x >> 6;
  const int b = blockIdx.x * 4 + wv;
  const int g = (lane < Gg) ? lane : 0;

  float wih0[Ff], whh0[Hh], wih1[Hh], whh1[Hh];
#pragma unroll
  for (int f = 0; f < Ff; ++f) wih0[f] = Wih0[g * Ff + f];
#pragma unroll
  for (int k = 0; k < Hh; ++k) whh0[k] = Whh0[g * Hh + k];
#pragma unroll
  for (int k = 0; k < Hh; ++k) wih1[k] = Wih1[g * Hh + k];
#pragma unroll
  for (int k = 0; k < Hh; ++k) whh1[k] = Whh1[g * Hh + k];
  const float bi0 = bih0[g], bh0 = bhh0[g], bi1 = bih1[g], bh1 = bhh1[g];

  float sA[Hh], sB[Hh];
#pragma unroll
  for (int k = 0; k < Hh; ++k) { sA[k] = 0.f; sB[k] = 0.f; }
  float hmA = 0.f, hmB = 0.f, y0 = 0.f, y1 = 0.f;

  const float* xrow = x + (size_t)b * (Tt * Ff);
  const int addrR = ((lane >= 40) ? (lane - 40) : lane) * 4;
  const int addrZ = ((lane >= 40) ? (lane - 20) : lane) * 4;
  const int jm = (lane >= 40 && lane < Gg) ? lane - 40 : 0;

  if (lane < 14) {
    __builtin_amdgcn_global_load_lds((gas_uchar*)(xrow + lane * 4),
                                     (las_uchar*)&xstage[wv][0][0], 16, 0, 0);
  }

#pragma unroll 1
  for (int t = 0; t < Tt; ++t) {
    const float* nxt = xrow + ((t < Tt - 1) ? Ff : 0);
    if (lane < 14) {
      __builtin_amdgcn_global_load_lds((gas_uchar*)(nxt + lane * 4),
                                       (las_uchar*)&xstage[wv][(t + 1) & 1][0], 16, 0, 0);
    }
    asm volatile("s_waitcnt vmcnt(1)" ::: "memory");
    const float4* xs = (const float4*)&xstage[wv][t & 1][0];
    {
      float a0 = bi0, a1 = 0.f, a2 = 0.f, a3 = 0.f;
#pragma unroll
      for (int i = 0; i < 14; ++i) {
        float4 xv = xs[i];
        a0 = fmaf(xv.x, wih0[4 * i + 0], a0);
        a1 = fmaf(xv.y, wih0[4 * i + 1], a1);
        a2 = fmaf(xv.z, wih0[4 * i + 2], a2);
        a3 = fmaf(xv.w, wih0[4 * i + 3], a3);
      }
      float ig = (a0 + a1) + (a2 + a3);
      float h0 = bh0, h1v = 0.f;
#pragma unroll
      for (int k = 0; k < Hh; k += 2) {
        h0 = fmaf(sA[k + 0], whh0[k + 0], h0);
        h1v = fmaf(sA[k + 1], whh0[k + 1], h1v);
      }
      float hg = h0 + h1v;
      gru_cell(ig, hg, addrR, addrZ, hmA);
#pragma unroll
      for (int j = 0; j < Hh; ++j) sA[j] = rdlane(hmA, 40 + j);
    }
    {
      float a0 = bi1, a1 = 0.f;
#pragma unroll
      for (int k = 0; k < Hh; k += 2) {
        a0 = fmaf(sA[k + 0], wih1[k + 0], a0);
        a1 = fmaf(sA[k + 1], wih1[k + 1], a1);
      }
      float ig = a0 + a1;
      float h0 = bh1, h1v = 0.f;
#pragma unroll
      for (int k = 0; k < Hh; k += 2) {
        h0 = fmaf(sB[k + 0], whh1[k + 0], h0);
        h1v = fmaf(sB[k + 1], whh1[k + 1], h1v);
      }
      float hg = h0 + h1v;
      gru_cell(ig, hg, addrR, addrZ, hmB);
#pragma unroll
      for (int j = 0; j < Hh; ++j) sB[j] = rdlane(hmB, 40 + j);
    }
    {
      float2 wv2 = *(const float2*)&weff[(t * Hh + jm) * 2];
      y0 = fmaf(hmB, wv2.x, y0);
      y1 = fmaf(hmB, wv2.y, y1);
    }
    xrow += Ff;
  }

  if (!(lane >= 40 && lane < Gg)) { y0 = 0.f; y1 = 0.f; }
#pragma unroll
  for (int off = 32; off >= 1; off >>= 1) {
    y0 += __shfl_xor(y0, off, 64);
    y1 += __shfl_xor(y1, off, 64);
  }
  if (lane == 0) {
    float be0 = ws[WS_BEFF + 0], be1 = ws[WS_BEFF + 1];
    float2 out = make_float2(y0 + be0, y1 + be1);
    *(float2*)(y + (size_t)b * 2) = out;
  }
}

extern "C" void kernel_launch(void* const* d_in, const int* in_sizes, int n_in,
                              void* d_out, int out_size, void* d_ws, size_t ws_size,
                              hipStream_t stream) {
  const float* x    = (const float*)d_in[0];
  const float* Wih0 = (const float*)d_in[1];
  const float* Whh0 = (const float*)d_in[2];
  const float* bih0 = (const float*)d_in[3];
  const float* bhh0 = (const float*)d_in[4];
  const float* Wih1 = (const float*)d_in[5];
  const float* Whh1 = (const float*)d_in[6];
  const float* bih1 = (const float*)d_in[7];
  const float* bhh1 = (const float*)d_in[8];
  const float* Wfc1 = (const float*)d_in[9];
  const float* bfc1 = (const float*)d_in[10];
  const float* Wfc2 = (const float*)d_in[11];
  const float* bfc2 = (const float*)d_in[12];
  float* ws = (float*)d_ws;
  float* y  = (float*)d_out;

  prep_all<<<18, 256, 0, stream>>>(Wfc1, bfc1, Wfc2, bfc2, Wih0, ws);

  if (ws_size >= WS_NEED_BYTES) {
    float* xp = ws + WS_XP;
    xproj_kernel<<<BT / 256, 256, 0, stream>>>(x, bih0, ws + WS_WT, xp);
    gru_scan_xp4<<<Bsz / 16, 256, 0, stream>>>(xp, Whh0, bhh0, Wih1, bih1,
                                               Whh1, bhh1, ws, y);
  } else {
    gru_scan_fb<<<Bsz / 4, 256, 0, stream>>>(x, Wih0, Whh0, bih0, bhh0,
                                             Wih1, Whh1, bih1, bhh1, ws, y);
  }
}

// Round 2
// 566.643 us; speedup vs baseline: 1.1366x; 1.0930x over previous
//
#include <hip/hip_runtime.h>

// B=16384, T=56, F=56, H=20, 3H=60, FC1=128, NC=2
// R6: (1) scan: 2 elems/wave (grid 2048 -> 2x TLP), layer-1 h2 broadcasts via
// per-wave LDS row (1 ds_write + 5 uniform ds_read_b128 replaces 20 readlanes),
// v_pk_add_f32 reductions. hA2 SGPR-pair persistence kept (serves 2 uses).
// (2) xproj: gate-paired v_pk_fma_f32 (weights repacked by prep into
// (g,g+1)-pair layout, consumed as SGPR operand) -> halves xproj VALU issues.

#define Bsz  16384
#define Tt   56
#define Ff   56
#define Hh   20
#define Gg   60
#define FC1n 128
#define THn  1120  // T*H
#define BT   (Bsz * Tt)

// ws float layout: [0..2239] weff, [2240..2241] beff, [2242..5601] WT2 (56*30*2),
// [5632 ..) xp (BT*60 floats)
#define WS_WEFF 0
#define WS_BEFF 2240
#define WS_WT   2242
#define WS_XP   5632
#define WS_NEED_BYTES ((size_t)(WS_XP + (size_t)BT * Gg) * 4)

typedef __attribute__((address_space(1))) const unsigned char gas_uchar;
typedef __attribute__((address_space(3))) unsigned char las_uchar;
typedef __attribute__((ext_vector_type(2))) float f32x2;

__device__ __forceinline__ float rdlane(float v, int l) {
  return __uint_as_float(__builtin_amdgcn_readlane(__float_as_uint(v), l));
}
__device__ __forceinline__ float bperm(int addr, float v) {
  return __uint_as_float(__builtin_amdgcn_ds_bpermute(addr, __float_as_uint(v)));
}
__device__ __forceinline__ float fast_rcp(float x) { return __builtin_amdgcn_rcpf(x); }
__device__ __forceinline__ float sigmoid_fast(float x) { return fast_rcp(1.0f + __expf(-x)); }
__device__ __forceinline__ float tanh_fast(float x) { return 1.0f - 2.0f * fast_rcp(1.0f + __expf(2.0f * x)); }

__device__ __forceinline__ f32x2 mk2(float a, float b) { f32x2 r; r.x = a; r.y = b; return r; }

// packed fma, SGPR-pair first operand (h broadcasts / x broadcast)
__device__ __forceinline__ f32x2 pkfma_s(f32x2 hs, f32x2 wv, f32x2 c) {
  f32x2 d;
  asm("v_pk_fma_f32 %0, %1, %2, %3" : "=v"(d) : "s"(hs), "v"(wv), "v"(c));
  return d;
}
// packed fma, all-VGPR operands
__device__ __forceinline__ f32x2 pkfma_v(f32x2 a, f32x2 b, f32x2 c) {
  f32x2 d;
  asm("v_pk_fma_f32 %0, %1, %2, %3" : "=v"(d) : "v"(a), "v"(b), "v"(c));
  return d;
}
// packed fma, SGPR-pair weight operand (xproj: uniform weights)
__device__ __forceinline__ f32x2 pkfma_w(f32x2 xx, f32x2 w, f32x2 c) {
  f32x2 d;
  asm("v_pk_fma_f32 %0, %1, %2, %3" : "=v"(d) : "v"(xx), "s"(w), "v"(c));
  return d;
}
__device__ __forceinline__ f32x2 pkadd(f32x2 a, f32x2 b) {
  f32x2 d;
  asm("v_pk_add_f32 %0, %1, %2" : "=v"(d) : "v"(a), "v"(b));
  return d;
}

__device__ __forceinline__ void gru_cell(float xg, float hg, int addrR, int addrZ, float& hm) {
  float sg = sigmoid_fast(xg + hg);     // r on lanes 0..19, z on 20..39
  float rr = bperm(addrR, sg);
  float nn = tanh_fast(fmaf(rr, hg, xg));
  float zz = bperm(addrZ, sg);
  hm = fmaf(zz, hm - nn, nn);           // n + z*(h-n)
}

// ---------------- prep: W_eff, b_eff, and gate-paired W_ih0 ----------------
// WT2 layout: [f=0..55][p=0..29][c=0..1] -> Wih0[(2p+c)*Ff + f]
__global__ void prep_all(const float* __restrict__ Wfc1, const float* __restrict__ bfc1,
                         const float* __restrict__ Wfc2, const float* __restrict__ bfc2,
                         const float* __restrict__ Wih0, float* __restrict__ ws) {
  int i = blockIdx.x * blockDim.x + threadIdx.x;
  if (i < THn) {
    float s0a = 0.f, s1a = 0.f, s0b = 0.f, s1b = 0.f;
    float s0c = 0.f, s1c = 0.f, s0d = 0.f, s1d = 0.f;
#pragma unroll 4
    for (int j = 0; j < FC1n; j += 4) {
      float wa = Wfc1[(j + 0) * THn + i];
      float wb = Wfc1[(j + 1) * THn + i];
      float wc = Wfc1[(j + 2) * THn + i];
      float wd = Wfc1[(j + 3) * THn + i];
      s0a = fmaf(wa, Wfc2[j + 0], s0a); s1a = fmaf(wa, Wfc2[FC1n + j + 0], s1a);
      s0b = fmaf(wb, Wfc2[j + 1], s0b); s1b = fmaf(wb, Wfc2[FC1n + j + 1], s1b);
      s0c = fmaf(wc, Wfc2[j + 2], s0c); s1c = fmaf(wc, Wfc2[FC1n + j + 2], s1c);
      s0d = fmaf(wd, Wfc2[j + 3], s0d); s1d = fmaf(wd, Wfc2[FC1n + j + 3], s1d);
    }
    ws[WS_WEFF + i * 2 + 0] = (s0a + s0b) + (s0c + s0d);
    ws[WS_WEFF + i * 2 + 1] = (s1a + s1b) + (s1c + s1d);
  } else if (i < THn + 2) {
    int c = i - THn;
    float s = bfc2[c];
    for (int j = 0; j < FC1n; ++j) s = fmaf(bfc1[j], Wfc2[c * FC1n + j], s);
    ws[WS_BEFF + c] = s;
  } else if (i < THn + 2 + Ff * Gg) {
    int j = i - (THn + 2);          // j = f*60 + p*2 + c
    int f = j / 60;
    int rem = j % 60;
    int p = rem >> 1, c = rem & 1;
    ws[WS_WT + j] = Wih0[(2 * p + c) * Ff + f];
  }
}

// ---------------- xproj v3: LDS-staged x, gate-paired pk_fma ----------------
#define PadW 57
__global__ __launch_bounds__(256, 2) void xproj_kernel(
    const float* __restrict__ x, const float* __restrict__ bih0,
    const float* __restrict__ wschunk /* ws+WS_WT */, float* __restrict__ xp) {
  __shared__ float xs[256 * PadW];  // 58368 B
  const int tid = threadIdx.x;
  const size_t blk0 = (size_t)blockIdx.x * 256;  // first row of this block

  const float4* xg = (const float4*)(x + blk0 * Ff);
#pragma unroll
  for (int i = 0; i < 14; ++i) {
    int p = i * 256 + tid;
    float4 v = xg[p];                 // coalesced 16B/lane
    int r = p / 14, c = p % 14;
    *(float4*)&xs[r * PadW + c * 4] = v;
  }
  __syncthreads();

  f32x2 acc2[30];
  const f32x2* b2 = (const f32x2*)bih0;  // uniform -> s_load
#pragma unroll
  for (int p = 0; p < 30; ++p) acc2[p] = b2[p];

  const f32x2* wt2 = (const f32x2*)wschunk;  // [56][30] pairs, wave-uniform
#pragma unroll 1
  for (int f4 = 0; f4 < 14; ++f4) {
    float4 xv = *(const float4*)&xs[tid * PadW + f4 * 4];
    const f32x2* w0 = wt2 + (size_t)(f4 * 4) * 30;
    {
      f32x2 xx = mk2(xv.x, xv.x);
#pragma unroll
      for (int p = 0; p < 30; ++p) acc2[p] = pkfma_w(xx, w0[p], acc2[p]);
    }
    {
      f32x2 xx = mk2(xv.y, xv.y);
      const f32x2* w = w0 + 30;
#pragma unroll
      for (int p = 0; p < 30; ++p) acc2[p] = pkfma_w(xx, w[p], acc2[p]);
    }
    {
      f32x2 xx = mk2(xv.z, xv.z);
      const f32x2* w = w0 + 60;
#pragma unroll
      for (int p = 0; p < 30; ++p) acc2[p] = pkfma_w(xx, w[p], acc2[p]);
    }
    {
      f32x2 xx = mk2(xv.w, xv.w);
      const f32x2* w = w0 + 90;
#pragma unroll
      for (int p = 0; p < 30; ++p) acc2[p] = pkfma_w(xx, w[p], acc2[p]);
    }
  }
  float4* out = (float4*)(xp + (blk0 + tid) * Gg);
#pragma unroll
  for (int q = 0; q < 15; ++q)
    out[q] = make_float4(acc2[2 * q].x, acc2[2 * q].y, acc2[2 * q + 1].x, acc2[2 * q + 1].y);
}

// ---------------- scan: 2 elems/wave, LDS h2 broadcast, pk dots ----------------
__global__ __launch_bounds__(256, 4) void gru_scan_xp2(
    const float* __restrict__ xp,
    const float* __restrict__ Whh0, const float* __restrict__ bhh0,
    const float* __restrict__ Wih1, const float* __restrict__ bih1,
    const float* __restrict__ Whh1, const float* __restrict__ bhh1,
    const float* __restrict__ ws, float* __restrict__ y) {
  __shared__ float weff[2 * THn + 2];
  __shared__ __align__(16) float hstage[4][2][64];  // [wave][e][lane]
  for (int idx = threadIdx.x; idx < 2 * THn + 2; idx += 256) weff[idx] = ws[idx];
  __syncthreads();

  const int lane = threadIdx.x & 63;
  const int wv = threadIdx.x >> 6;
  const int b0 = (blockIdx.x * 4 + wv) * 2;  // elems b0, b0+1
  const int g = (lane < Gg) ? lane : 0;

  // per-lane weight rows as f32x2 pairs over k
  f32x2 whh0p[10], wih1p[10], whh1p[10];
#pragma unroll
  for (int i = 0; i < 10; ++i) whh0p[i] = *(const f32x2*)&Whh0[g * Hh + 2 * i];
#pragma unroll
  for (int i = 0; i < 10; ++i) wih1p[i] = *(const f32x2*)&Wih1[g * Hh + 2 * i];
#pragma unroll
  for (int i = 0; i < 10; ++i) whh1p[i] = *(const f32x2*)&Whh1[g * Hh + 2 * i];

  const f32x2 cb0  = mk2(bhh0[g], 0.f);
  const f32x2 cb1i = mk2(bih1[g], 0.f);
  const f32x2 cb1h = mk2(bhh1[g], 0.f);
  const f32x2 zz2  = mk2(0.f, 0.f);

  float hmA[2] = {0.f, 0.f};
  float hmB[2] = {0.f, 0.f};
  // persisted SGPR-pair broadcasts of hmA; reused by layer-1 ih (t) and
  // layer-0 hh (t+1).
  f32x2 hA2[2][10];
#pragma unroll
  for (int e = 0; e < 2; ++e)
#pragma unroll
    for (int i = 0; i < 10; ++i) hA2[e][i] = zz2;

  // h2 state staged in a per-wave LDS row; pre-zero for t=0
  hstage[wv][0][lane] = 0.f;
  hstage[wv][1][lane] = 0.f;

  float ya[2] = {0.f, 0.f};
  float yb[2] = {0.f, 0.f};

  const int addrR = ((lane >= 40) ? (lane - 40) : lane) * 4;
  const int addrZ = ((lane >= 40) ? (lane - 20) : lane) * 4;
  const int jm = (lane >= 40 && lane < Gg) ? lane - 40 : 0;

  const float* xpb = xp + (size_t)b0 * (Tt * Gg);
  int off[2];
  float xc[2], xn[2];
#pragma unroll
  for (int e = 0; e < 2; ++e) { off[e] = e * (Tt * Gg) + g; xc[e] = xpb[off[e]]; }

#pragma unroll 1
  for (int t = 0; t < Tt; ++t) {
    if (t < Tt - 1) {  // uniform branch: prefetch next step's xp
#pragma unroll
      for (int e = 0; e < 2; ++e) xn[e] = xpb[off[e] + Gg];
    }
    // ---- layer 0: hg = Whh0 . h1(t-1) + bh0 (hA2 SGPR reuse) ----
#pragma unroll
    for (int e = 0; e < 2; ++e) {
      f32x2 a = pkfma_s(hA2[e][0], whh0p[0], cb0);
      f32x2 b = pkfma_s(hA2[e][1], whh0p[1], zz2);
#pragma unroll
      for (int i = 2; i < 10; i += 2) {
        a = pkfma_s(hA2[e][i], whh0p[i], a);
        b = pkfma_s(hA2[e][i + 1], whh0p[i + 1], b);
      }
      f32x2 s = pkadd(a, b);
      float hg = s.x + s.y;
      gru_cell(xc[e], hg, addrR, addrZ, hmA[e]);
      // refresh broadcasts of the NEW hmA into SGPR pairs
#pragma unroll
      for (int i = 0; i < 10; ++i)
        hA2[e][i] = mk2(rdlane(hmA[e], 40 + 2 * i), rdlane(hmA[e], 41 + 2 * i));
    }
    // ---- layer 1: ig = Wih1 . h1(t) (SGPR), hg = Whh1 . h2(t-1) (LDS quads) ----
#pragma unroll
    for (int e = 0; e < 2; ++e) {
      f32x2 ai = pkfma_s(hA2[e][0], wih1p[0], cb1i);
      f32x2 bi = pkfma_s(hA2[e][1], wih1p[1], zz2);
#pragma unroll
      for (int i = 2; i < 10; i += 2) {
        ai = pkfma_s(hA2[e][i], wih1p[i], ai);
        bi = pkfma_s(hA2[e][i + 1], wih1p[i + 1], bi);
      }
      const float4* hb = (const float4*)&hstage[wv][e][40];  // uniform -> broadcast
      float4 q0 = hb[0], q1 = hb[1], q2 = hb[2], q3 = hb[3], q4 = hb[4];
      f32x2 ah = pkfma_v(mk2(q0.x, q0.y), whh1p[0], cb1h);
      f32x2 bh = pkfma_v(mk2(q0.z, q0.w), whh1p[1], zz2);
      ah = pkfma_v(mk2(q1.x, q1.y), whh1p[2], ah);
      bh = pkfma_v(mk2(q1.z, q1.w), whh1p[3], bh);
      ah = pkfma_v(mk2(q2.x, q2.y), whh1p[4], ah);
      bh = pkfma_v(mk2(q2.z, q2.w), whh1p[5], bh);
      ah = pkfma_v(mk2(q3.x, q3.y), whh1p[6], ah);
      bh = pkfma_v(mk2(q3.z, q3.w), whh1p[7], bh);
      ah = pkfma_v(mk2(q4.x, q4.y), whh1p[8], ah);
      bh = pkfma_v(mk2(q4.z, q4.w), whh1p[9], bh);
      f32x2 si = pkadd(ai, bi);
      float ig = si.x + si.y;
      f32x2 sh = pkadd(ah, bh);
      float hg = sh.x + sh.y;
      gru_cell(ig, hg, addrR, addrZ, hmB[e]);
      hstage[wv][e][lane] = hmB[e];  // stage new h2 for t+1
    }
    // ---- FC accumulation (lane 40+j holds h2[t][j]) ----
    {
      float2 wv2 = *(const float2*)&weff[(t * Hh + jm) * 2];
#pragma unroll
      for (int e = 0; e < 2; ++e) {
        ya[e] = fmaf(hmB[e], wv2.x, ya[e]);
        yb[e] = fmaf(hmB[e], wv2.y, yb[e]);
      }
    }
#pragma unroll
    for (int e = 0; e < 2; ++e) { xc[e] = xn[e]; off[e] += Gg; }
  }

  const bool active = (lane >= 40 && lane < Gg);
#pragma unroll
  for (int e = 0; e < 2; ++e) {
    if (!active) { ya[e] = 0.f; yb[e] = 0.f; }
  }
#pragma unroll
  for (int off2 = 32; off2 >= 1; off2 >>= 1) {
#pragma unroll
    for (int e = 0; e < 2; ++e) {
      ya[e] += __shfl_xor(ya[e], off2, 64);
      yb[e] += __shfl_xor(yb[e], off2, 64);
    }
  }
  if (lane == 0) {
    float be0 = weff[WS_BEFF], be1 = weff[WS_BEFF + 1];
    float4 o0 = make_float4(ya[0] + be0, yb[0] + be1, ya[1] + be0, yb[1] + be1);
    *(float4*)(y + (size_t)b0 * 2) = o0;
  }
}

// ---------------- fallback scan (ws too small for xp) ----------------
__global__ __launch_bounds__(256) void gru_scan_fb(
    const float* __restrict__ x,
    const float* __restrict__ Wih0, const float* __restrict__ Whh0,
    const float* __restrict__ bih0, const float* __restrict__ bhh0,
    const float* __restrict__ Wih1, const float* __restrict__ Whh1,
    const float* __restrict__ bih1, const float* __restrict__ bhh1,
    const float* __restrict__ ws, float* __restrict__ y) {
  __shared__ float weff[2 * THn];
  __shared__ __align__(16) float xstage[4][2][Ff];
  for (int idx = threadIdx.x; idx < 2 * THn; idx += 256) weff[idx] = ws[idx];
  __syncthreads();

  const int lane = threadIdx.x & 63;
  const int wv = threadIdx.x >> 6;
  const int b = blockIdx.x * 4 + wv;
  const int g = (lane < Gg) ? lane : 0;

  float wih0[Ff], whh0[Hh], wih1[Hh], whh1[Hh];
#pragma unroll
  for (int f = 0; f < Ff; ++f) wih0[f] = Wih0[g * Ff + f];
#pragma unroll
  for (int k = 0; k < Hh; ++k) whh0[k] = Whh0[g * Hh + k];
#pragma unroll
  for (int k = 0; k < Hh; ++k) wih1[k] = Wih1[g * Hh + k];
#pragma unroll
  for (int k = 0; k < Hh; ++k) whh1[k] = Whh1[g * Hh + k];
  const float bi0 = bih0[g], bh0 = bhh0[g], bi1 = bih1[g], bh1 = bhh1[g];

  float sA[Hh], sB[Hh];
#pragma unroll
  for (int k = 0; k < Hh; ++k) { sA[k] = 0.f; sB[k] = 0.f; }
  float hmA = 0.f, hmB = 0.f, y0 = 0.f, y1 = 0.f;

  const float* xrow = x + (size_t)b * (Tt * Ff);
  const int addrR = ((lane >= 40) ? (lane - 40) : lane) * 4;
  const int addrZ = ((lane >= 40) ? (lane - 20) : lane) * 4;
  const int jm = (lane >= 40 && lane < Gg) ? lane - 40 : 0;

  if (lane < 14) {
    __builtin_amdgcn_global_load_lds((gas_uchar*)(xrow + lane * 4),
                                     (las_uchar*)&xstage[wv][0][0], 16, 0, 0);
  }

#pragma unroll 1
  for (int t = 0; t < Tt; ++t) {
    const float* nxt = xrow + ((t < Tt - 1) ? Ff : 0);
    if (lane < 14) {
      __builtin_amdgcn_global_load_lds((gas_uchar*)(nxt + lane * 4),
                                       (las_uchar*)&xstage[wv][(t + 1) & 1][0], 16, 0, 0);
    }
    asm volatile("s_waitcnt vmcnt(1)" ::: "memory");
    const float4* xs = (const float4*)&xstage[wv][t & 1][0];
    {
      float a0 = bi0, a1 = 0.f, a2 = 0.f, a3 = 0.f;
#pragma unroll
      for (int i = 0; i < 14; ++i) {
        float4 xv = xs[i];
        a0 = fmaf(xv.x, wih0[4 * i + 0], a0);
        a1 = fmaf(xv.y, wih0[4 * i + 1], a1);
        a2 = fmaf(xv.z, wih0[4 * i + 2], a2);
        a3 = fmaf(xv.w, wih0[4 * i + 3], a3);
      }
      float ig = (a0 + a1) + (a2 + a3);
      float h0 = bh0, h1v = 0.f;
#pragma unroll
      for (int k = 0; k < Hh; k += 2) {
        h0 = fmaf(sA[k + 0], whh0[k + 0], h0);
        h1v = fmaf(sA[k + 1], whh0[k + 1], h1v);
      }
      float hg = h0 + h1v;
      gru_cell(ig, hg, addrR, addrZ, hmA);
#pragma unroll
      for (int j = 0; j < Hh; ++j) sA[j] = rdlane(hmA, 40 + j);
    }
    {
      float a0 = bi1, a1 = 0.f;
#pragma unroll
      for (int k = 0; k < Hh; k += 2) {
        a0 = fmaf(sA[k + 0], wih1[k + 0], a0);
        a1 = fmaf(sA[k + 1], wih1[k + 1], a1);
      }
      float ig = a0 + a1;
      float h0 = bh1, h1v = 0.f;
#pragma unroll
      for (int k = 0; k < Hh; k += 2) {
        h0 = fmaf(sB[k + 0], whh1[k + 0], h0);
        h1v = fmaf(sB[k + 1], whh1[k + 1], h1v);
      }
      float hg = h0 + h1v;
      gru_cell(ig, hg, addrR, addrZ, hmB);
#pragma unroll
      for (int j = 0; j < Hh; ++j) sB[j] = rdlane(hmB, 40 + j);
    }
    {
      float2 wv2 = *(const float2*)&weff[(t * Hh + jm) * 2];
      y0 = fmaf(hmB, wv2.x, y0);
      y1 = fmaf(hmB, wv2.y, y1);
    }
    xrow += Ff;
  }

  if (!(lane >= 40 && lane < Gg)) { y0 = 0.f; y1 = 0.f; }
#pragma unroll
  for (int off = 32; off >= 1; off >>= 1) {
    y0 += __shfl_xor(y0, off, 64);
    y1 += __shfl_xor(y1, off, 64);
  }
  if (lane == 0) {
    float be0 = ws[WS_BEFF + 0], be1 = ws[WS_BEFF + 1];
    float2 out = make_float2(y0 + be0, y1 + be1);
    *(float2*)(y + (size_t)b * 2) = out;
  }
}

extern "C" void kernel_launch(void* const* d_in, const int* in_sizes, int n_in,
                              void* d_out, int out_size, void* d_ws, size_t ws_size,
                              hipStream_t stream) {
  const float* x    = (const float*)d_in[0];
  const float* Wih0 = (const float*)d_in[1];
  const float* Whh0 = (const float*)d_in[2];
  const float* bih0 = (const float*)d_in[3];
  const float* bhh0 = (const float*)d_in[4];
  const float* Wih1 = (const float*)d_in[5];
  const float* Whh1 = (const float*)d_in[6];
  const float* bih1 = (const float*)d_in[7];
  const float* bhh1 = (const float*)d_in[8];
  const float* Wfc1 = (const float*)d_in[9];
  const float* bfc1 = (const float*)d_in[10];
  const float* Wfc2 = (const float*)d_in[11];
  const float* bfc2 = (const float*)d_in[12];
  float* ws = (float*)d_ws;
  float* y  = (float*)d_out;

  prep_all<<<18, 256, 0, stream>>>(Wfc1, bfc1, Wfc2, bfc2, Wih0, ws);

  if (ws_size >= WS_NEED_BYTES) {
    float* xp = ws + WS_XP;
    xproj_kernel<<<BT / 256, 256, 0, stream>>>(x, bih0, ws + WS_WT, xp);
    gru_scan_xp2<<<Bsz / 8, 256, 0, stream>>>(xp, Whh0, bhh0, Wih1, bih1,
                                              Whh1, bhh1, ws, y);
  } else {
    gru_scan_fb<<<Bsz / 4, 256, 0, stream>>>(x, Wih0, Whh0, bih0, bhh0,
                                             Wih1, Whh1, bih1, bhh1, ws, y);
  }
}

// Round 4
// 517.330 us; speedup vs baseline: 1.2450x; 1.0953x over previous
//
#include <hip/hip_runtime.h>

// B=16384, T=56, F=56, H=20, 3H=60, FC1=128, NC=2
// R7 (resubmit; previous bench died to container-acquisition failure, not the
// kernel). FUSED: xproj folded into the scan kernel: per (t, elem) the wave
// stages the 56-float x row via one global_load_lds (28 lanes x 16B,
// double-buffered over t), broadcasts it with uniform ds_read_b128, and
// computes the ih0 dot with per-lane Wih0 row pairs (v_pk_fma_f32).
// Eliminates the xp intermediate (220MB write + 105MB fetch), the separate
// xproj kernel, and shrinks the workspace from 226MB to 9KB. Scan core
// (pk dots, SGPR hA2 persistence, LDS h2 broadcast) unchanged from R6.

#define Bsz  16384
#define Tt   56
#define Ff   56
#define Hh   20
#define Gg   60
#define FC1n 128
#define THn  1120  // T*H

// ws float layout: [0..2239] weff, [2240..2241] beff
#define WS_WEFF 0
#define WS_BEFF 2240

typedef __attribute__((address_space(1))) const unsigned char gas_uchar;
typedef __attribute__((address_space(3))) unsigned char las_uchar;
typedef __attribute__((ext_vector_type(2))) float f32x2;

__device__ __forceinline__ float rdlane(float v, int l) {
  return __uint_as_float(__builtin_amdgcn_readlane(__float_as_uint(v), l));
}
__device__ __forceinline__ float bperm(int addr, float v) {
  return __uint_as_float(__builtin_amdgcn_ds_bpermute(addr, __float_as_uint(v)));
}
__device__ __forceinline__ float fast_rcp(float x) { return __builtin_amdgcn_rcpf(x); }
__device__ __forceinline__ float sigmoid_fast(float x) { return fast_rcp(1.0f + __expf(-x)); }
__device__ __forceinline__ float tanh_fast(float x) { return 1.0f - 2.0f * fast_rcp(1.0f + __expf(2.0f * x)); }

__device__ __forceinline__ f32x2 mk2(float a, float b) { f32x2 r; r.x = a; r.y = b; return r; }

// packed fma, SGPR-pair first operand (persisted h broadcasts)
__device__ __forceinline__ f32x2 pkfma_s(f32x2 hs, f32x2 wv, f32x2 c) {
  f32x2 d;
  asm("v_pk_fma_f32 %0, %1, %2, %3" : "=v"(d) : "s"(hs), "v"(wv), "v"(c));
  return d;
}
// packed fma, all-VGPR operands (LDS-broadcast values)
__device__ __forceinline__ f32x2 pkfma_v(f32x2 a, f32x2 b, f32x2 c) {
  f32x2 d;
  asm("v_pk_fma_f32 %0, %1, %2, %3" : "=v"(d) : "v"(a), "v"(b), "v"(c));
  return d;
}
__device__ __forceinline__ f32x2 pkadd(f32x2 a, f32x2 b) {
  f32x2 d;
  asm("v_pk_add_f32 %0, %1, %2" : "=v"(d) : "v"(a), "v"(b));
  return d;
}

__device__ __forceinline__ void gru_cell(float xg, float hg, int addrR, int addrZ, float& hm) {
  float sg = sigmoid_fast(xg + hg);     // r on lanes 0..19, z on 20..39
  float rr = bperm(addrR, sg);
  float nn = tanh_fast(fmaf(rr, hg, xg));
  float zz = bperm(addrZ, sg);
  hm = fmaf(zz, hm - nn, nn);           // n + z*(h-n)
}

// ---------------- prep: W_eff = Wfc2 @ Wfc1 (folded FC), b_eff ----------------
__global__ void prep_all(const float* __restrict__ Wfc1, const float* __restrict__ bfc1,
                         const float* __restrict__ Wfc2, const float* __restrict__ bfc2,
                         float* __restrict__ ws) {
  int i = blockIdx.x * blockDim.x + threadIdx.x;
  if (i < THn) {
    float s0a = 0.f, s1a = 0.f, s0b = 0.f, s1b = 0.f;
    float s0c = 0.f, s1c = 0.f, s0d = 0.f, s1d = 0.f;
#pragma unroll 4
    for (int j = 0; j < FC1n; j += 4) {
      float wa = Wfc1[(j + 0) * THn + i];
      float wb = Wfc1[(j + 1) * THn + i];
      float wc = Wfc1[(j + 2) * THn + i];
      float wd = Wfc1[(j + 3) * THn + i];
      s0a = fmaf(wa, Wfc2[j + 0], s0a); s1a = fmaf(wa, Wfc2[FC1n + j + 0], s1a);
      s0b = fmaf(wb, Wfc2[j + 1], s0b); s1b = fmaf(wb, Wfc2[FC1n + j + 1], s1b);
      s0c = fmaf(wc, Wfc2[j + 2], s0c); s1c = fmaf(wc, Wfc2[FC1n + j + 2], s1c);
      s0d = fmaf(wd, Wfc2[j + 3], s0d); s1d = fmaf(wd, Wfc2[FC1n + j + 3], s1d);
    }
    ws[WS_WEFF + i * 2 + 0] = (s0a + s0b) + (s0c + s0d);
    ws[WS_WEFF + i * 2 + 1] = (s1a + s1b) + (s1c + s1d);
  } else if (i < THn + 2) {
    int c = i - THn;
    float s = bfc2[c];
    for (int j = 0; j < FC1n; ++j) s = fmaf(bfc1[j], Wfc2[c * FC1n + j], s);
    ws[WS_BEFF + c] = s;
  }
}

// ---------------- fused scan: 2 elems/wave, in-loop xproj ----------------
__global__ __launch_bounds__(256, 3) void gru_fused(
    const float* __restrict__ x,
    const float* __restrict__ Wih0, const float* __restrict__ bih0,
    const float* __restrict__ Whh0, const float* __restrict__ bhh0,
    const float* __restrict__ Wih1, const float* __restrict__ bih1,
    const float* __restrict__ Whh1, const float* __restrict__ bhh1,
    const float* __restrict__ ws, float* __restrict__ y) {
  __shared__ float weff[2 * THn + 2];
  __shared__ __align__(16) float xstage[4][2][2 * Ff];  // [wave][buf][e0 row | e1 row]
  __shared__ __align__(16) float hstage[4][2][64];      // [wave][e][lane]
  for (int idx = threadIdx.x; idx < 2 * THn + 2; idx += 256) weff[idx] = ws[idx];
  __syncthreads();

  const int lane = threadIdx.x & 63;
  const int wv = threadIdx.x >> 6;
  const int b0 = (blockIdx.x * 4 + wv) * 2;  // elems b0, b0+1
  const int g = (lane < Gg) ? lane : 0;

  // per-lane weight rows as f32x2 pairs over input index
  f32x2 wih0p[28], whh0p[10], wih1p[10], whh1p[10];
#pragma unroll
  for (int i = 0; i < 28; ++i) wih0p[i] = *(const f32x2*)&Wih0[g * Ff + 2 * i];
#pragma unroll
  for (int i = 0; i < 10; ++i) whh0p[i] = *(const f32x2*)&Whh0[g * Hh + 2 * i];
#pragma unroll
  for (int i = 0; i < 10; ++i) wih1p[i] = *(const f32x2*)&Wih1[g * Hh + 2 * i];
#pragma unroll
  for (int i = 0; i < 10; ++i) whh1p[i] = *(const f32x2*)&Whh1[g * Hh + 2 * i];

  const f32x2 cbi0 = mk2(bih0[g], 0.f);
  const f32x2 cb0  = mk2(bhh0[g], 0.f);
  const f32x2 cb1i = mk2(bih1[g], 0.f);
  const f32x2 cb1h = mk2(bhh1[g], 0.f);
  const f32x2 zz2  = mk2(0.f, 0.f);

  float hmA[2] = {0.f, 0.f};
  float hmB[2] = {0.f, 0.f};
  f32x2 hA2[2][10];  // persisted SGPR-pair broadcasts of hmA
#pragma unroll
  for (int e = 0; e < 2; ++e)
#pragma unroll
    for (int i = 0; i < 10; ++i) hA2[e][i] = zz2;

  hstage[wv][0][lane] = 0.f;
  hstage[wv][1][lane] = 0.f;

  float ya[2] = {0.f, 0.f};
  float yb[2] = {0.f, 0.f};

  const int addrR = ((lane >= 40) ? (lane - 40) : lane) * 4;
  const int addrZ = ((lane >= 40) ? (lane - 20) : lane) * 4;
  const int jm = (lane >= 40 && lane < Gg) ? lane - 40 : 0;

  // per-lane x source: lanes 0..13 cover elem b0's row (16B chunks),
  // lanes 14..27 cover elem b0+1's row. Dest is lds_base + lane*16 (HW rule),
  // so [e0 row | e1 row] lands contiguously.
  const int le = (lane >= 14) ? 1 : 0;
  const int lc = lane - le * 14;
  const float* xsrc = x + (size_t)(b0 + le) * (Tt * Ff) + lc * 4;

  if (lane < 28) {
    __builtin_amdgcn_global_load_lds((gas_uchar*)xsrc,
                                     (las_uchar*)&xstage[wv][0][0], 16, 0, 0);
  }

#pragma unroll 1
  for (int t = 0; t < Tt; ++t) {
    const float* nxt = xsrc + ((t < Tt - 1) ? Ff : 0);
    if (lane < 28) {
      __builtin_amdgcn_global_load_lds((gas_uchar*)nxt,
                                       (las_uchar*)&xstage[wv][(t + 1) & 1][0], 16, 0, 0);
    }
    asm volatile("s_waitcnt vmcnt(1)" ::: "memory");
    // ---- layer 0: ig = Wih0 . x(t) + bi0 (LDS broadcast), hg = Whh0 . h1(t-1) ----
#pragma unroll
    for (int e = 0; e < 2; ++e) {
      const float4* xb = (const float4*)&xstage[wv][t & 1][e * Ff];  // uniform
      float4 q = xb[0];
      f32x2 a = pkfma_v(mk2(q.x, q.y), wih0p[0], cbi0);
      f32x2 b = pkfma_v(mk2(q.z, q.w), wih0p[1], zz2);
#pragma unroll
      for (int i = 1; i < 14; ++i) {
        q = xb[i];
        a = pkfma_v(mk2(q.x, q.y), wih0p[2 * i], a);
        b = pkfma_v(mk2(q.z, q.w), wih0p[2 * i + 1], b);
      }
      f32x2 sx = pkadd(a, b);
      f32x2 c = pkfma_s(hA2[e][0], whh0p[0], cb0);
      f32x2 d = pkfma_s(hA2[e][1], whh0p[1], zz2);
#pragma unroll
      for (int i = 2; i < 10; i += 2) {
        c = pkfma_s(hA2[e][i], whh0p[i], c);
        d = pkfma_s(hA2[e][i + 1], whh0p[i + 1], d);
      }
      f32x2 sh = pkadd(c, d);
      float xg = sx.x + sx.y;
      float hg = sh.x + sh.y;
      gru_cell(xg, hg, addrR, addrZ, hmA[e]);
      // refresh broadcasts of the NEW hmA into SGPR pairs (serves layer-1 ih
      // at t and layer-0 hh at t+1)
#pragma unroll
      for (int i = 0; i < 10; ++i)
        hA2[e][i] = mk2(rdlane(hmA[e], 40 + 2 * i), rdlane(hmA[e], 41 + 2 * i));
    }
    // ---- layer 1: ig = Wih1 . h1(t) (SGPR), hg = Whh1 . h2(t-1) (LDS quads) ----
#pragma unroll
    for (int e = 0; e < 2; ++e) {
      f32x2 ai = pkfma_s(hA2[e][0], wih1p[0], cb1i);
      f32x2 bi = pkfma_s(hA2[e][1], wih1p[1], zz2);
#pragma unroll
      for (int i = 2; i < 10; i += 2) {
        ai = pkfma_s(hA2[e][i], wih1p[i], ai);
        bi = pkfma_s(hA2[e][i + 1], wih1p[i + 1], bi);
      }
      const float4* hb = (const float4*)&hstage[wv][e][40];  // uniform -> broadcast
      float4 q0 = hb[0], q1 = hb[1], q2 = hb[2], q3 = hb[3], q4 = hb[4];
      f32x2 ah = pkfma_v(mk2(q0.x, q0.y), whh1p[0], cb1h);
      f32x2 bh = pkfma_v(mk2(q0.z, q0.w), whh1p[1], zz2);
      ah = pkfma_v(mk2(q1.x, q1.y), whh1p[2], ah);
      bh = pkfma_v(mk2(q1.z, q1.w), whh1p[3], bh);
      ah = pkfma_v(mk2(q2.x, q2.y), whh1p[4], ah);
      bh = pkfma_v(mk2(q2.z, q2.w), whh1p[5], bh);
      ah = pkfma_v(mk2(q3.x, q3.y), whh1p[6], ah);
      bh = pkfma_v(mk2(q3.z, q3.w), whh1p[7], bh);
      ah = pkfma_v(mk2(q4.x, q4.y), whh1p[8], ah);
      bh = pkfma_v(mk2(q4.z, q4.w), whh1p[9], bh);
      f32x2 si = pkadd(ai, bi);
      float ig = si.x + si.y;
      f32x2 sh = pkadd(ah, bh);
      float hg = sh.x + sh.y;
      gru_cell(ig, hg, addrR, addrZ, hmB[e]);
      hstage[wv][e][lane] = hmB[e];  // stage new h2 for t+1
    }
    // ---- FC accumulation (lane 40+j holds h2[t][j]) ----
    {
      float2 wv2 = *(const float2*)&weff[(t * Hh + jm) * 2];
#pragma unroll
      for (int e = 0; e < 2; ++e) {
        ya[e] = fmaf(hmB[e], wv2.x, ya[e]);
        yb[e] = fmaf(hmB[e], wv2.y, yb[e]);
      }
    }
    xsrc += Ff;
  }

  const bool active = (lane >= 40 && lane < Gg);
#pragma unroll
  for (int e = 0; e < 2; ++e) {
    if (!active) { ya[e] = 0.f; yb[e] = 0.f; }
  }
#pragma unroll
  for (int off2 = 32; off2 >= 1; off2 >>= 1) {
#pragma unroll
    for (int e = 0; e < 2; ++e) {
      ya[e] += __shfl_xor(ya[e], off2, 64);
      yb[e] += __shfl_xor(yb[e], off2, 64);
    }
  }
  if (lane == 0) {
    float be0 = weff[WS_BEFF], be1 = weff[WS_BEFF + 1];
    float4 o0 = make_float4(ya[0] + be0, yb[0] + be1, ya[1] + be0, yb[1] + be1);
    *(float4*)(y + (size_t)b0 * 2) = o0;
  }
}

extern "C" void kernel_launch(void* const* d_in, const int* in_sizes, int n_in,
                              void* d_out, int out_size, void* d_ws, size_t ws_size,
                              hipStream_t stream) {
  const float* x    = (const float*)d_in[0];
  const float* Wih0 = (const float*)d_in[1];
  const float* Whh0 = (const float*)d_in[2];
  const float* bih0 = (const float*)d_in[3];
  const float* bhh0 = (const float*)d_in[4];
  const float* Wih1 = (const float*)d_in[5];
  const float* Whh1 = (const float*)d_in[6];
  const float* bih1 = (const float*)d_in[7];
  const float* bhh1 = (const float*)d_in[8];
  const float* Wfc1 = (const float*)d_in[9];
  const float* bfc1 = (const float*)d_in[10];
  const float* Wfc2 = (const float*)d_in[11];
  const float* bfc2 = (const float*)d_in[12];
  float* ws = (float*)d_ws;
  float* y  = (float*)d_out;

  prep_all<<<5, 256, 0, stream>>>(Wfc1, bfc1, Wfc2, bfc2, ws);
  gru_fused<<<Bsz / 8, 256, 0, stream>>>(x, Wih0, bih0, Whh0, bhh0,
                                         Wih1, bih1, Whh1, bhh1, ws, y);
}